// Round 4
// baseline (362.436 us; speedup 1.0000x reference)
//
#include <hip/hip_runtime.h>

// PConvLinear: B=2, N=60000, K=16, C_in=64, C_add=3, C_mid=16.
// Phase A (operand-swapped): pconv^T[m][c] = sum_k Wn[k][m] * feat[k][c]
//   via mfma_f32_16x16x16f16, gathers land DIRECTLY in B-fragments.
//   This round: inF pre-converted to f16 in lane-packed layout
//   inF16[n][ml*4+ct] so each lane's 4 ct-values are ONE 8B f16x4 load
//   (VMEM/pt 24->12, cvts/pt -16, gather bytes halved); depth-4 pipeline
//   (all 4 points' gathers in flight). Falls back to fp32 gather if ws small.
// Phase B: out[32 x 128] = sP @ LWh^T over 34 K-chunks of 32 (f16 MFMA),
//   rotating 2-deep b-prefetch, first two chunks issued pre-barrier.
#define NPTS  60000
#define NBLK  1875          // blocks per batch (32 points each)
#define FP    1088          // F padded to 34*32 for K-chunking
#define PSTR  1096          // sP row stride (f16): 548 dw, %32=4
#define SPBYTES (32 * PSTR * 2)           // 70,144 B
#define LWH_BYTES   (128 * FP * 2)        // 278,528 B
#define INF16_BYTES (2 * NPTS * 64 * 2)   // 15,360,000 B
#define WS_NEED     (LWH_BYTES + INF16_BYTES)

typedef _Float16 f16x4 __attribute__((ext_vector_type(4)));
typedef _Float16 f16x8 __attribute__((ext_vector_type(8)));
typedef float    f32x4 __attribute__((ext_vector_type(4)));

// ---- pre-kernel: linear_weight fp32 [128][1072] -> f16 LWh2[ch=34][o=128][e=32]
// Phase-B load for o-tile o0 is a fully-coalesced 1KB wave transaction:
// byte = ch*8192 + (o0+ml)*64 + q*16.
__global__ void __launch_bounds__(256)
cvt_lw_kernel(const float* __restrict__ LW, _Float16* __restrict__ LWh) {
    const int o = blockIdx.x;
    for (int f = threadIdx.x; f < FP; f += 256) {
        const float v = (f < 1072) ? LW[o * 1072 + f] : 0.f;
        LWh[(f >> 5) * (128 * 32) + o * 32 + (f & 31)] = (_Float16)v;
    }
}

// ---- pre-kernel: inF fp32 [2N][64] -> f16 lane-packed [2N][64]:
// element c = ct*16+ml lands at slot ml*4+ct, so gather lane (q,ml) reads
// its 4 ct-values as one aligned f16x4 at [idx*64 + ml*4].
__global__ void __launch_bounds__(256)
cvt_inf_kernel(const float* __restrict__ inF, _Float16* __restrict__ inF16) {
    const int tid = blockIdx.x * 256 + threadIdx.x;
    if (tid >= 2 * NPTS * 64) return;
    const int c = tid & 63;
    const int n = tid >> 6;
    inF16[(n << 6) + ((c & 15) << 2) + (c >> 4)] = (_Float16)inF[tid];
}

template<bool F16P> struct GRegs;
template<> struct GRegs<true>  { f16x4 fv[4];    float wv[4]; float av[4]; };
template<> struct GRegs<false> { float fv[4][4]; float wv[4]; float av[4]; };

static __device__ __forceinline__ void issue_gather16(
    const _Float16* __restrict__ inF16, const float* __restrict__ Wn,
    const float* __restrict__ addF, int bbase, int base_nk,
    int ind_lane, int i, int q, int ml, bool mlo, GRegs<true>& g)
{
    #pragma unroll
    for (int j = 0; j < 4; ++j) {
        const int k   = q * 4 + j;
        const int idx = __shfl(ind_lane, i * 16 + k, 64);   // ds_bpermute
        g.fv[j] = *(const f16x4*)(inF16 + (bbase + idx) * 64 + ml * 4); // 8B b64
        g.wv[j] = Wn[(base_nk + k) * 16 + ml];
        g.av[j] = mlo ? addF[(base_nk + k) * 3 + ml] : 0.f;
    }
}

static __device__ __forceinline__ void issue_gather32(
    const float* __restrict__ inF, const float* __restrict__ Wn,
    const float* __restrict__ addF, int bbase, int base_nk,
    int ind_lane, int i, int q, int ml, bool mlo, GRegs<false>& g)
{
    #pragma unroll
    for (int j = 0; j < 4; ++j) {
        const int k   = q * 4 + j;
        const int idx = __shfl(ind_lane, i * 16 + k, 64);   // ds_bpermute
        const float* fp = inF + (bbase + idx) * 64 + ml;
        #pragma unroll
        for (int ct = 0; ct < 4; ++ct)
            g.fv[ct][j] = fp[ct * 16];
        g.wv[j] = Wn[(base_nk + k) * 16 + ml];
        g.av[j] = mlo ? addF[(base_nk + k) * 3 + ml] : 0.f;
    }
}

// D[row=m=q*4+r][col=c=ml]; f = c*16 + m -> d[0..3] are CONSECUTIVE f.
// 8B slot index swizzled: qsw = q ^ (((ml>>2)&1)<<1) (per-thread const).
template<bool F16P>
static __device__ __forceinline__ void compute_point(
    const GRegs<F16P>& g, _Float16* sProw, int qsw, int ml, bool mlo)
{
    const f32x4 z4 = {0.f, 0.f, 0.f, 0.f};
    f16x4 aW, bA;
    #pragma unroll
    for (int j = 0; j < 4; ++j) { aW[j] = (_Float16)g.wv[j]; bA[j] = (_Float16)g.av[j]; }

    #pragma unroll
    for (int ct = 0; ct < 4; ++ct) {
        f16x4 bF;
        #pragma unroll
        for (int j = 0; j < 4; ++j) {
            if constexpr (F16P) bF[j] = g.fv[j][ct];           // reg extract
            else                bF[j] = (_Float16)g.fv[ct][j]; // cvt
        }
        const f32x4 d = __builtin_amdgcn_mfma_f32_16x16x16f16(aW, bF, z4, 0, 0, 0);
        f16x4 dh;
        #pragma unroll
        for (int r = 0; r < 4; ++r) dh[r] = (_Float16)d[r];
        *(f16x4*)&sProw[(ct * 16 + ml) * 16 + qsw * 4] = dh;
    }
    // c-tile 4: c = 64+ml valid for ml<3 (f in [1024,1072)); ml<3 -> qsw==q.
    const f32x4 d = __builtin_amdgcn_mfma_f32_16x16x16f16(aW, bA, z4, 0, 0, 0);
    if (mlo) {
        f16x4 dh;
        #pragma unroll
        for (int r = 0; r < 4; ++r) dh[r] = (_Float16)d[r];
        *(f16x4*)&sProw[(64 + ml) * 16 + qsw * 4] = dh;
    }
}

template<bool F16P>
__global__ void __launch_bounds__(512, 4)
pconv_linear_mfma(const float* __restrict__ inF,   // [2][60000][64]
                  const _Float16* __restrict__ inF16, // lane-packed (or null)
                  const int*   __restrict__ inds,  // [2][60000][16]
                  const float* __restrict__ Wn,    // [2][60000][16][16]
                  const float* __restrict__ addF,  // [2][60000][16][3]
                  const _Float16* __restrict__ LWh,// LWh2[34][128][32] f16 (d_ws)
                  const float* __restrict__ bias,  // [128]
                  float*       __restrict__ out)   // [2][60000][128]
{
    extern __shared__ __align__(16) _Float16 sP[];   // [32][PSTR] f16, 70,144 B

    const int t    = threadIdx.x;
    const int lane = t & 63;
    const int w    = t >> 6;        // wave 0..7
    const int q    = lane >> 4;     // quad 0..3
    const int ml   = lane & 15;
    const bool mlo = (ml < 3);
    const int qsw  = q ^ (((ml >> 2) & 1) << 1);

    const int bid   = blockIdx.x;
    const int b     = bid / NBLK;
    const int n0    = (bid - b * NBLK) * 32;
    const int bbase = b * NPTS;

    // lane l holds inds[point w*4 + (l>>4)][k = l&15]
    const int ind_lane = inds[(bbase + n0 + w * 4) * 16 + lane];

    // zero the pad cols f in [1072,1088) for all 32 rows
    sP[(t >> 4) * PSTR + 1072 + (t & 15)] = (_Float16)0.f;

    // ======== Phase A: direct-to-register gather ========
    const int nk0 = (bbase + n0 + w * 4) * 16;
    _Float16* sPw = sP + (w * 4) * PSTR;
    if constexpr (F16P) {
        // depth-4: all 48 VMEM in flight before first consume
        GRegs<true> g0, g1, g2, g3;
        issue_gather16(inF16, Wn, addF, bbase, nk0,      ind_lane, 0, q, ml, mlo, g0);
        issue_gather16(inF16, Wn, addF, bbase, nk0 + 16, ind_lane, 1, q, ml, mlo, g1);
        issue_gather16(inF16, Wn, addF, bbase, nk0 + 32, ind_lane, 2, q, ml, mlo, g2);
        issue_gather16(inF16, Wn, addF, bbase, nk0 + 48, ind_lane, 3, q, ml, mlo, g3);
        compute_point<true>(g0, sPw,            qsw, ml, mlo);
        compute_point<true>(g1, sPw + PSTR,     qsw, ml, mlo);
        compute_point<true>(g2, sPw + 2 * PSTR, qsw, ml, mlo);
        compute_point<true>(g3, sPw + 3 * PSTR, qsw, ml, mlo);
    } else {
        // fallback (ws too small): round-3 depth-2 fp32 gather
        GRegs<false> g0, g1;
        issue_gather32(inF, Wn, addF, bbase, nk0,      ind_lane, 0, q, ml, mlo, g0);
        issue_gather32(inF, Wn, addF, bbase, nk0 + 16, ind_lane, 1, q, ml, mlo, g1);
        compute_point<false>(g0, sPw,            qsw, ml, mlo);
        issue_gather32(inF, Wn, addF, bbase, nk0 + 32, ind_lane, 2, q, ml, mlo, g0);
        compute_point<false>(g1, sPw + PSTR,     qsw, ml, mlo);
        issue_gather32(inF, Wn, addF, bbase, nk0 + 48, ind_lane, 3, q, ml, mlo, g1);
        compute_point<false>(g0, sPw + 2 * PSTR, qsw, ml, mlo);
        compute_point<false>(g1, sPw + 3 * PSTR, qsw, ml, mlo);
    }

    // pre-barrier issue of Phase-B chunks 0,1 (independent of LDS)
    const int o0 = w * 16;
    const _Float16* bP = LWh + (o0 + ml) * 32 + q * 8;     // + ch*4096 per chunk
    f16x8 bcur = *(const f16x8*)(bP);
    f16x8 bnxt = *(const f16x8*)(bP + 4096);
    __syncthreads();

    // ======== Phase B: out[32 x 128] = sP @ LWh^T, MFMA over 34 K-chunks ========
    // Wave w owns o-tile o0 for BOTH 16-pt sub-tiles: one b load -> 2 MFMAs.
    // Read-side of the slot swizzle: logical f16x8 at f = ch*32 + q*8 sits at
    // row*PSTR + ch*32 + (q>>1)*16 + ((q&1) ^ ((ch>>1)&1))*8.
    const float bz = bias[o0 + ml];
    f32x4 acc0 = {0.f, 0.f, 0.f, 0.f};
    f32x4 acc1 = {0.f, 0.f, 0.f, 0.f};
    const _Float16* aP0 = sP + ml * PSTR + (q >> 1) * 16 + (q & 1) * 8;
    const _Float16* aP1 = aP0 + 16 * PSTR;
    const int flip = (q & 1) ? -8 : 8;                     // f16 units

    #pragma unroll 2
    for (int ch = 0; ch < 34; ++ch) {
        const int chf = (ch + 2 < 34) ? (ch + 2) : 33;
        f16x8 bfut = *(const f16x8*)(bP + chf * 4096);     // 2-deep rotation
        const int off = ch * 32 + ((ch & 2) ? flip : 0);
        f16x8 a0 = *(const f16x8*)(aP0 + off);             // ds_read_b128
        f16x8 a1 = *(const f16x8*)(aP1 + off);
        acc0 = __builtin_amdgcn_mfma_f32_16x16x32_f16(a0, bcur, acc0, 0, 0, 0);
        acc1 = __builtin_amdgcn_mfma_f32_16x16x32_f16(a1, bcur, acc1, 0, 0, 0);
        bcur = bnxt; bnxt = bfut;
    }

    // ======== Epilogue: bias + store (rows p = q*4+r and +16, cols o0+ml) ========
    float* ob = out + (bbase + n0 + q * 4) * 128 + o0 + ml;
    #pragma unroll
    for (int r = 0; r < 4; ++r)
        ob[r * 128] = acc0[r] + bz;
    ob += 16 * 128;
    #pragma unroll
    for (int r = 0; r < 4; ++r)
        ob[r * 128] = acc1[r] + bz;
}

extern "C" void kernel_launch(void* const* d_in, const int* in_sizes, int n_in,
                              void* d_out, int out_size, void* d_ws, size_t ws_size,
                              hipStream_t stream)
{
    const float* inF  = (const float*)d_in[0];
    const int*   inds = (const int*)  d_in[1];
    const float* Wn   = (const float*)d_in[2];
    const float* addF = (const float*)d_in[3];
    const float* LW   = (const float*)d_in[4];
    const float* bias = (const float*)d_in[5];
    float* out = (float*)d_out;
    _Float16* LWh = (_Float16*)d_ws;

    const bool f16p = (ws_size >= (size_t)WS_NEED);

    // opt-in to >64KB dynamic LDS (host-side attr set, graph-capture safe)
    hipFuncSetAttribute((const void*)pconv_linear_mfma<true>,
                        hipFuncAttributeMaxDynamicSharedMemorySize, SPBYTES);
    hipFuncSetAttribute((const void*)pconv_linear_mfma<false>,
                        hipFuncAttributeMaxDynamicSharedMemorySize, SPBYTES);

    cvt_lw_kernel<<<dim3(128), dim3(256), 0, stream>>>(LW, LWh);
    if (f16p) {
        _Float16* inF16 = (_Float16*)((char*)d_ws + LWH_BYTES);
        cvt_inf_kernel<<<dim3((2 * NPTS * 64 + 255) / 256), dim3(256), 0, stream>>>(
            inF, inF16);
        pconv_linear_mfma<true><<<dim3(2 * NBLK), dim3(512), SPBYTES, stream>>>(
            inF, inF16, inds, Wn, addF, LWh, bias, out);
    } else {
        pconv_linear_mfma<false><<<dim3(2 * NBLK), dim3(512), SPBYTES, stream>>>(
            inF, (const _Float16*)nullptr, inds, Wn, addF, LWh, bias, out);
    }
}

// Round 5
// 330.802 us; speedup vs baseline: 1.0956x; 1.0956x over previous
//
#include <hip/hip_runtime.h>

// PConvLinear: B=2, N=60000, K=16, C_in=64, C_add=3, C_mid=16.
// Persistent-block fused pipeline:
//   250 blocks (1/CU) x 512 thr, 15 tiles of 32 points each (exactly 3750).
//   LWh lives in REGISTERS: wave w owns o-tile w*16 for all tiles -> 34
//   f16x8 b-fragments (136 VGPR) loaded once; Phase B has ZERO VMEM.
//   sP double-buffered (2x70KB LDS); gathers for tile i+1 issued during
//   Phase A of tile i, in flight across all of Phase B (ILP latency hiding).
//   One barrier per tile.
#define NPTS  60000
#define NBLK  1875          // 32-pt tiles per batch
#define FP    1088          // F padded to 34*32
#define PSTR  1096          // sP row stride (f16)
#define HALF  (32 * PSTR)   // f16 elems per sP buffer
#define SPBYTES    (2 * HALF * 2)      // 140,288 B
#define SPBYTES_FB (32 * PSTR * 2)     // 70,144 B (fallback)
#define LWH_BYTES   (128 * FP * 2)     // 278,528 B
#define INF16_BYTES (2 * NPTS * 64 * 2)
#define WS_NEED     (LWH_BYTES + INF16_BYTES)
#define TILES   15
#define NBLOCKS 250

typedef _Float16 f16x4 __attribute__((ext_vector_type(4)));
typedef _Float16 f16x8 __attribute__((ext_vector_type(8)));
typedef float    f32x4 __attribute__((ext_vector_type(4)));

// ---- pre-kernel: linear_weight fp32 [128][1072] -> f16 LWh2[ch=34][o=128][e=32]
__global__ void __launch_bounds__(256)
cvt_lw_kernel(const float* __restrict__ LW, _Float16* __restrict__ LWh) {
    const int o = blockIdx.x;
    for (int f = threadIdx.x; f < FP; f += 256) {
        const float v = (f < 1072) ? LW[o * 1072 + f] : 0.f;
        LWh[(f >> 5) * (128 * 32) + o * 32 + (f & 31)] = (_Float16)v;
    }
}

// ---- pre-kernel: inF fp32 [2N][64] -> f16 lane-packed: c=ct*16+ml at slot ml*4+ct
__global__ void __launch_bounds__(256)
cvt_inf_kernel(const float* __restrict__ inF, _Float16* __restrict__ inF16) {
    const int tid = blockIdx.x * 256 + threadIdx.x;
    if (tid >= 2 * NPTS * 64) return;
    const int c = tid & 63;
    const int n = tid >> 6;
    inF16[(n << 6) + ((c & 15) << 2) + (c >> 4)] = (_Float16)inF[tid];
}

struct GR { f16x4 fv[4]; float wv[4]; };   // 12 VGPR per point in flight

static __device__ __forceinline__ void issue_gather16(
    const _Float16* __restrict__ inF16, const float* __restrict__ Wn,
    int bbase, int base_nk, int ind_lane, int i, int q, int ml, GR& g)
{
    #pragma unroll
    for (int j = 0; j < 4; ++j) {
        const int k   = q * 4 + j;
        const int idx = __shfl(ind_lane, i * 16 + k, 64);   // ds_bpermute
        g.fv[j] = *(const f16x4*)(inF16 + (bbase + idx) * 64 + ml * 4); // 8B
        g.wv[j] = Wn[(base_nk + k) * 16 + ml];
    }
}

// D[row=m=q*4+r][col=c=ml]; f = c*16+m -> d[0..3] CONSECUTIVE f (one b64 write).
// 8B slot swizzle qsw = q ^ (((ml>>2)&1)<<1). addF loaded HERE (issued first,
// consumed by the LAST mfma -> ~4 MFMAs of internal latency cover).
static __device__ __forceinline__ void compute_point(
    const GR& g, const float* __restrict__ aFp,  // addF + base_nk*3 + ml
    _Float16* sProw, int qsw, int q, int ml, bool mlo)
{
    float av[4];
    #pragma unroll
    for (int j = 0; j < 4; ++j)
        av[j] = mlo ? aFp[(q * 4 + j) * 3] : 0.f;

    const f32x4 z4 = {0.f, 0.f, 0.f, 0.f};
    f16x4 aW;
    #pragma unroll
    for (int j = 0; j < 4; ++j) aW[j] = (_Float16)g.wv[j];

    #pragma unroll
    for (int ct = 0; ct < 4; ++ct) {
        f16x4 bF;
        #pragma unroll
        for (int j = 0; j < 4; ++j) bF[j] = g.fv[j][ct];
        const f32x4 d = __builtin_amdgcn_mfma_f32_16x16x16f16(aW, bF, z4, 0, 0, 0);
        f16x4 dh;
        #pragma unroll
        for (int r = 0; r < 4; ++r) dh[r] = (_Float16)d[r];
        *(f16x4*)&sProw[(ct * 16 + ml) * 16 + qsw * 4] = dh;
    }
    f16x4 bA;
    #pragma unroll
    for (int j = 0; j < 4; ++j) bA[j] = (_Float16)av[j];
    const f32x4 d = __builtin_amdgcn_mfma_f32_16x16x16f16(aW, bA, z4, 0, 0, 0);
    if (mlo) {     // c-tile 4: c=64..66, rows unswizzled (qsw==q for ml<3)
        f16x4 dh;
        #pragma unroll
        for (int r = 0; r < 4; ++r) dh[r] = (_Float16)d[r];
        *(f16x4*)&sProw[(64 + ml) * 16 + qsw * 4] = dh;
    }
}

__global__ void __launch_bounds__(512, 2)
pconv_persistent(const _Float16* __restrict__ inF16, // lane-packed f16 (d_ws)
                 const int*   __restrict__ inds,     // [2][60000][16]
                 const float* __restrict__ Wn,       // [2][60000][16][16]
                 const float* __restrict__ addF,     // [2][60000][16][3]
                 const _Float16* __restrict__ LWh,   // LWh2[34][128][32] (d_ws)
                 const float* __restrict__ bias,     // [128]
                 float*       __restrict__ out)      // [2][60000][128]
{
    extern __shared__ __align__(16) _Float16 sP[];   // [2][32][PSTR]

    const int t    = threadIdx.x;
    const int lane = t & 63;
    const int w    = t >> 6;        // wave 0..7
    const int q    = lane >> 4;
    const int ml   = lane & 15;
    const bool mlo = (ml < 3);
    const int qsw  = q ^ (((ml >> 2) & 1) << 1);

    // zero pad cols f in [1072,1088) of BOTH buffers once (never overwritten)
    sP[(t >> 4) * PSTR + 1072 + (t & 15)] = (_Float16)0.f;
    sP[HALF + (t >> 4) * PSTR + 1072 + (t & 15)] = (_Float16)0.f;

    // ---- prologue: per-wave LWh o-slice into registers (34 x f16x8 = 136 VGPR)
    const int o0 = w * 16;
    const _Float16* bPw = LWh + (o0 + ml) * 32 + q * 8;
    f16x8 bfr[34];
    #pragma unroll
    for (int ch = 0; ch < 34; ++ch)
        bfr[ch] = *(const f16x8*)(bPw + ch * 4096);
    const float bz = bias[o0 + ml];

    // ---- tile 0 meta + first gathers
    int gt  = blockIdx.x * TILES;
    int bC  = gt / NBLK;
    int n0C = (gt - bC * NBLK) * 32;
    int bbC = bC * NPTS;
    int nkC = (bbC + n0C + w * 4) * 16;
    GR g0, g1, g2, g3;
    {
        const int ind0 = inds[nkC + lane];
        issue_gather16(inF16, Wn, bbC, nkC,      ind0, 0, q, ml, g0);
        issue_gather16(inF16, Wn, bbC, nkC + 16, ind0, 1, q, ml, g1);
        issue_gather16(inF16, Wn, bbC, nkC + 32, ind0, 2, q, ml, g2);
        issue_gather16(inF16, Wn, bbC, nkC + 48, ind0, 3, q, ml, g3);
    }

    for (int tt = 0; tt < TILES; ++tt) {
        const bool more = (tt + 1 < TILES);
        // next-tile meta + ind (early load, used mid-phase-A)
        int bbN = bbC, n0N = n0C, nkN = nkC, indN = 0;
        if (more) {
            const int gtn = gt + 1;
            const int bN  = gtn / NBLK;
            n0N = (gtn - bN * NBLK) * 32;
            bbN = bN * NPTS;
            nkN = (bbN + n0N + w * 4) * 16;
            indN = inds[nkN + lane];
        }

        _Float16* sPc = sP + (tt & 1) * HALF;
        _Float16* sPw = sPc + (w * 4) * PSTR;
        const float* aFp = addF + nkC * 3 + ml;

        // ---- Phase A: consume tile tt, refill gathers for tile tt+1
        compute_point(g0, aFp,       sPw,            qsw, q, ml, mlo);
        compute_point(g1, aFp + 48,  sPw + PSTR,     qsw, q, ml, mlo);
        if (more) {
            issue_gather16(inF16, Wn, bbN, nkN,      indN, 0, q, ml, g0);
            issue_gather16(inF16, Wn, bbN, nkN + 16, indN, 1, q, ml, g1);
        }
        compute_point(g2, aFp + 96,  sPw + 2 * PSTR, qsw, q, ml, mlo);
        compute_point(g3, aFp + 144, sPw + 3 * PSTR, qsw, q, ml, mlo);
        if (more) {
            issue_gather16(inF16, Wn, bbN, nkN + 32, indN, 2, q, ml, g2);
            issue_gather16(inF16, Wn, bbN, nkN + 48, indN, 3, q, ml, g3);
        }
        __syncthreads();   // sP[tt&1] complete; also fences prev-tile readers

        // ---- Phase B: out[32 x 128] = sP @ (reg-resident LWh^T), no VMEM
        // swizzle read: f16x8 at f=ch*32+q*8 sits at row*PSTR + ch*32
        //               + (q>>1)*16 + ((q&1)^((ch>>1)&1))*8
        f32x4 acc0 = {0.f, 0.f, 0.f, 0.f};
        f32x4 acc1 = {0.f, 0.f, 0.f, 0.f};
        const _Float16* aP0 = sPc + ml * PSTR + (q >> 1) * 16 + (q & 1) * 8;
        const _Float16* aP1 = aP0 + 16 * PSTR;
        const int flip = (q & 1) ? -8 : 8;
        #pragma unroll
        for (int ch = 0; ch < 34; ++ch) {
            const int off = ch * 32 + ((ch & 2) ? flip : 0);
            f16x8 a0 = *(const f16x8*)(aP0 + off);     // ds_read_b128
            f16x8 a1 = *(const f16x8*)(aP1 + off);
            acc0 = __builtin_amdgcn_mfma_f32_16x16x32_f16(a0, bfr[ch], acc0, 0, 0, 0);
            acc1 = __builtin_amdgcn_mfma_f32_16x16x32_f16(a1, bfr[ch], acc1, 0, 0, 0);
        }

        // ---- epilogue: bias + store (rows q*4+r and +16, cols o0+ml)
        float* ob = out + (bbC + n0C + q * 4) * 128 + o0 + ml;
        #pragma unroll
        for (int r = 0; r < 4; ++r)
            ob[r * 128] = acc0[r] + bz;
        ob += 16 * 128;
        #pragma unroll
        for (int r = 0; r < 4; ++r)
            ob[r * 128] = acc1[r] + bz;

        bbC = bbN; n0C = n0N; nkC = nkN; ++gt;
    }
}

// ================= fallback (ws too small): round-4 fp32-gather kernel =========
struct GR32 { float fv[4][4]; float wv[4]; float av[4]; };

static __device__ __forceinline__ void issue_gather32(
    const float* __restrict__ inF, const float* __restrict__ Wn,
    const float* __restrict__ addF, int bbase, int base_nk,
    int ind_lane, int i, int q, int ml, bool mlo, GR32& g)
{
    #pragma unroll
    for (int j = 0; j < 4; ++j) {
        const int k   = q * 4 + j;
        const int idx = __shfl(ind_lane, i * 16 + k, 64);
        const float* fp = inF + (bbase + idx) * 64 + ml;
        #pragma unroll
        for (int ct = 0; ct < 4; ++ct)
            g.fv[ct][j] = fp[ct * 16];
        g.wv[j] = Wn[(base_nk + k) * 16 + ml];
        g.av[j] = mlo ? addF[(base_nk + k) * 3 + ml] : 0.f;
    }
}

static __device__ __forceinline__ void compute_point32(
    const GR32& g, _Float16* sProw, int qsw, int ml, bool mlo)
{
    const f32x4 z4 = {0.f, 0.f, 0.f, 0.f};
    f16x4 aW, bA;
    #pragma unroll
    for (int j = 0; j < 4; ++j) { aW[j] = (_Float16)g.wv[j]; bA[j] = (_Float16)g.av[j]; }
    #pragma unroll
    for (int ct = 0; ct < 4; ++ct) {
        f16x4 bF;
        #pragma unroll
        for (int j = 0; j < 4; ++j) bF[j] = (_Float16)g.fv[ct][j];
        const f32x4 d = __builtin_amdgcn_mfma_f32_16x16x16f16(aW, bF, z4, 0, 0, 0);
        f16x4 dh;
        #pragma unroll
        for (int r = 0; r < 4; ++r) dh[r] = (_Float16)d[r];
        *(f16x4*)&sProw[(ct * 16 + ml) * 16 + qsw * 4] = dh;
    }
    const f32x4 d = __builtin_amdgcn_mfma_f32_16x16x16f16(aW, bA, z4, 0, 0, 0);
    if (mlo) {
        f16x4 dh;
        #pragma unroll
        for (int r = 0; r < 4; ++r) dh[r] = (_Float16)d[r];
        *(f16x4*)&sProw[(64 + ml) * 16 + qsw * 4] = dh;
    }
}

__global__ void __launch_bounds__(512, 4)
pconv_fallback(const float* __restrict__ inF, const int* __restrict__ inds,
               const float* __restrict__ Wn, const float* __restrict__ addF,
               const _Float16* __restrict__ LWh, const float* __restrict__ bias,
               float* __restrict__ out)
{
    extern __shared__ __align__(16) _Float16 sP[];
    const int t = threadIdx.x, lane = t & 63, w = t >> 6;
    const int q = lane >> 4, ml = lane & 15;
    const bool mlo = (ml < 3);
    const int qsw = q ^ (((ml >> 2) & 1) << 1);
    const int bid = blockIdx.x, b = bid / NBLK;
    const int n0 = (bid - b * NBLK) * 32, bbase = b * NPTS;
    const int ind_lane = inds[(bbase + n0 + w * 4) * 16 + lane];
    sP[(t >> 4) * PSTR + 1072 + (t & 15)] = (_Float16)0.f;

    const int nk0 = (bbase + n0 + w * 4) * 16;
    _Float16* sPw = sP + (w * 4) * PSTR;
    GR32 g0, g1;
    issue_gather32(inF, Wn, addF, bbase, nk0,      ind_lane, 0, q, ml, mlo, g0);
    issue_gather32(inF, Wn, addF, bbase, nk0 + 16, ind_lane, 1, q, ml, mlo, g1);
    compute_point32(g0, sPw,            qsw, ml, mlo);
    issue_gather32(inF, Wn, addF, bbase, nk0 + 32, ind_lane, 2, q, ml, mlo, g0);
    compute_point32(g1, sPw + PSTR,     qsw, ml, mlo);
    issue_gather32(inF, Wn, addF, bbase, nk0 + 48, ind_lane, 3, q, ml, mlo, g1);
    compute_point32(g0, sPw + 2 * PSTR, qsw, ml, mlo);
    compute_point32(g1, sPw + 3 * PSTR, qsw, ml, mlo);

    const int o0 = w * 16;
    const _Float16* bP = LWh + (o0 + ml) * 32 + q * 8;
    f16x8 bcur = *(const f16x8*)(bP);
    f16x8 bnxt = *(const f16x8*)(bP + 4096);
    __syncthreads();

    const float bz = bias[o0 + ml];
    f32x4 acc0 = {0.f, 0.f, 0.f, 0.f};
    f32x4 acc1 = {0.f, 0.f, 0.f, 0.f};
    const _Float16* aP0 = sP + ml * PSTR + (q >> 1) * 16 + (q & 1) * 8;
    const _Float16* aP1 = aP0 + 16 * PSTR;
    const int flip = (q & 1) ? -8 : 8;
    #pragma unroll 2
    for (int ch = 0; ch < 34; ++ch) {
        const int chf = (ch + 2 < 34) ? (ch + 2) : 33;
        f16x8 bfut = *(const f16x8*)(bP + chf * 4096);
        const int off = ch * 32 + ((ch & 2) ? flip : 0);
        f16x8 a0 = *(const f16x8*)(aP0 + off);
        f16x8 a1 = *(const f16x8*)(aP1 + off);
        acc0 = __builtin_amdgcn_mfma_f32_16x16x32_f16(a0, bcur, acc0, 0, 0, 0);
        acc1 = __builtin_amdgcn_mfma_f32_16x16x32_f16(a1, bcur, acc1, 0, 0, 0);
        bcur = bnxt; bnxt = bfut;
    }
    float* ob = out + (bbase + n0 + q * 4) * 128 + o0 + ml;
    #pragma unroll
    for (int r = 0; r < 4; ++r) ob[r * 128] = acc0[r] + bz;
    ob += 16 * 128;
    #pragma unroll
    for (int r = 0; r < 4; ++r) ob[r * 128] = acc1[r] + bz;
}

extern "C" void kernel_launch(void* const* d_in, const int* in_sizes, int n_in,
                              void* d_out, int out_size, void* d_ws, size_t ws_size,
                              hipStream_t stream)
{
    const float* inF  = (const float*)d_in[0];
    const int*   inds = (const int*)  d_in[1];
    const float* Wn   = (const float*)d_in[2];
    const float* addF = (const float*)d_in[3];
    const float* LW   = (const float*)d_in[4];
    const float* bias = (const float*)d_in[5];
    float* out = (float*)d_out;
    _Float16* LWh = (_Float16*)d_ws;

    const bool f16p = (ws_size >= (size_t)WS_NEED);

    hipFuncSetAttribute((const void*)pconv_persistent,
                        hipFuncAttributeMaxDynamicSharedMemorySize, SPBYTES);
    hipFuncSetAttribute((const void*)pconv_fallback,
                        hipFuncAttributeMaxDynamicSharedMemorySize, SPBYTES_FB);

    cvt_lw_kernel<<<dim3(128), dim3(256), 0, stream>>>(LW, LWh);
    if (f16p) {
        _Float16* inF16 = (_Float16*)((char*)d_ws + LWH_BYTES);
        cvt_inf_kernel<<<dim3((2 * NPTS * 64 + 255) / 256), dim3(256), 0, stream>>>(
            inF, inF16);
        pconv_persistent<<<dim3(NBLOCKS), dim3(512), SPBYTES, stream>>>(
            inF16, inds, Wn, addF, LWh, bias, out);
    } else {
        pconv_fallback<<<dim3(2 * NBLK), dim3(512), SPBYTES_FB, stream>>>(
            inF, inds, Wn, addF, LWh, bias, out);
    }
}